// Round 6
// baseline (40893.967 us; speedup 1.0000x reference)
//
#include <hip/hip_runtime.h>
#include <cstdint>
#include <cstddef>

// ---------------------------------------------------------------------------
// BaseDecoder: 128-step LSTM decoder with jax.random.categorical sampling.
//
// Structure per call (all on `stream`, graph-capture safe):
//   k_init                      : features mean-pool, x init (emb[1]), zero h/c,
//                                 zero winners/counters (ws is poisoned each call)
//   128 x { k_lstm, k_logits }  : LSTM step (z = x@K + h@R + b, cell update),
//                                 logits + gumbel + argmax + embed gather
//
// v6 = v5 lane split (8 cols x 4 batches per lane) + DEEP register pipeline.
//   v5 held only 3 loads in flight (depth-1 lookahead) -> weight stream
//   latency-bound at ~1/3 of its bandwidth floor. v6 ping-pongs GROUPS of
//   4 k-rows: weights double-buffered (8 dwordx4 in flight across each
//   128-FMA group), x issued before the weight prefetch so its vmcnt wait
//   (in-order retirement) leaves the weight loads outstanding.
//   VGPR: 64 W-bufs + 16 X + 32 acc + addressing ~= 124; __launch_bounds__
//   (512,4) pins <=128 so 2 blocks/CU (4 waves/SIMD) stay resident.
//   Per-output accumulation order (k ascending, same reduction tree) is
//   bit-identical to v5/v3.
//
// PRNG: JAX threefry, *partitionable* variant (default since jax 0.5):
//   split(key)  -> row_i = threefry(key, (0, i)) (both words)
//   bits(i)     = w0 ^ w1 of threefry(subkey, (0, i)), i = b*32000 + v
//   uniform     = bitcast((bits>>9)|0x3f800000) - 1, max(tiny, . + tiny)
//   gumbel      = -log(-log(u)); sample = argmax(logits + gumbel), first index
// Key chain computed on host (pure, same every call) and passed as args.
//
// ws layout (needs ~4.75 MB):
//   [0       ) winners  128*32 u64      (packed argmax, atomicMax)
//   [32768   ) cntA     128*16 u32      (lstm split-k group counters)
//   [40960   ) cntB     128    u32      (logits block counters)
//   [49152   ) xT       768*32 f32      (x transposed [row][batch]; rows 0-255
//                                        emb[sample], 256-767 features)
//   [147456  ) hb0      1024*32 f32     (h ping)
//   [278528  ) hb1      1024*32 f32     (h pong)
//   [409600  ) cT       1024*32 f32     (cell state [u][b])
//   [540672  ) zpart    8*4096*32 f32   (split-k partials of z)
// ---------------------------------------------------------------------------

#define VOCAB 32000
#define EMB 256
#define UNITS 1024
#define STEPS 128
#define BATCH 32
#define XROWS 768
#define TINYF 1.17549435e-38f

#define LD4(p) (*reinterpret_cast<const float4*>(p))

// Threefry-2x32, 20 rounds (matches jax._src.prng exactly).
__host__ __device__ __forceinline__ void tf2x32(uint32_t k0, uint32_t k1,
                                                uint32_t x0, uint32_t x1,
                                                uint32_t& o0, uint32_t& o1) {
  uint32_t ks2 = k0 ^ k1 ^ 0x1BD11BDAu;
#define TFR(r) { x0 += x1; x1 = (x1 << (r)) | (x1 >> (32 - (r))); x1 ^= x0; }
  x0 += k0; x1 += k1;
  TFR(13) TFR(15) TFR(26) TFR(6)  x0 += k1;  x1 += ks2 + 1u;
  TFR(17) TFR(29) TFR(16) TFR(24) x0 += ks2; x1 += k0 + 2u;
  TFR(13) TFR(15) TFR(26) TFR(6)  x0 += k0;  x1 += k1 + 3u;
  TFR(17) TFR(29) TFR(16) TFR(24) x0 += k1;  x1 += ks2 + 4u;
  TFR(13) TFR(15) TFR(26) TFR(6)  x0 += ks2; x1 += k0 + 5u;
#undef TFR
  o0 = x0; o1 = x1;
}

// 32 FMAs of one k-step: acc[c*4+bb] += w8[c] * x4[bb].
// All indices static after unroll -> pure register code.
__device__ __forceinline__ void fma_8x4(float* acc, const float4& wa,
                                        const float4& wb, const float4& x) {
  const float w8[8] = {wa.x, wa.y, wa.z, wa.w, wb.x, wb.y, wb.z, wb.w};
#pragma unroll
  for (int c = 0; c < 8; ++c) {
    float wv = w8[c];
    acc[c * 4 + 0] = fmaf(wv, x.x, acc[c * 4 + 0]);
    acc[c * 4 + 1] = fmaf(wv, x.y, acc[c * 4 + 1]);
    acc[c * 4 + 2] = fmaf(wv, x.z, acc[c * 4 + 2]);
    acc[c * 4 + 3] = fmaf(wv, x.w, acc[c * 4 + 3]);
  }
}

// ---------------------------------------------------------------------------
__global__ __launch_bounds__(256) void k_init(
    const float* __restrict__ img, const float* __restrict__ emb,
    float* __restrict__ xT, float* __restrict__ h0, float* __restrict__ cT,
    unsigned long long* __restrict__ winners, unsigned int* __restrict__ cntA,
    unsigned int* __restrict__ cntB) {
  int idx = blockIdx.x * 256 + threadIdx.x;
  if (idx < 16384) {                       // features: mean over 200 positions
    int b = idx >> 9, ch = idx & 511;
    const float* p = img + (size_t)b * 102400 + ch;
    float s = 0.f;
    for (int t = 0; t < 200; ++t) s += p[(size_t)t * 512];
    xT[(size_t)(256 + ch) * 32 + b] = s / 200.0f;
  } else if (idx < 24576) {                // start token embedding (row 1)
    int i2 = idx - 16384;
    int e = i2 >> 5, b = i2 & 31;
    xT[(size_t)e * 32 + b] = emb[256 + e];
  } else if (idx < 57344) {
    h0[idx - 24576] = 0.f;
  } else if (idx < 90112) {
    cT[idx - 57344] = 0.f;
  } else if (idx < 94208) {
    winners[idx - 90112] = 0ull;
  } else if (idx < 96256) {
    cntA[idx - 94208] = 0u;
  } else if (idx < 96384) {
    cntB[idx - 96256] = 0u;
  }
}

// ---------------------------------------------------------------------------
// LSTM step. Grid 512 = 64 column-tiles (64 of 4096 z cols) x 8 k-eighths.
// Block 512 = 8 wave-strips x 64 lanes; lane (cs=lane>>3, bg=lane&7) owns
// cols jt*64 + cs*8 + [0,8) x batches bg*4 + [0,4). Strip s covers k rows
// [e*224 + s*28, +28) = 7 groups of 4 (groups never straddle row 768: all
// group bases are multiples of 4). Last block of each group of 32 (same
// hidden-unit tile) performs the cell update into cT / hw.
__global__ __launch_bounds__(512, 4) void k_lstm(
    const float* __restrict__ Km, const float* __restrict__ Rm,
    const float* __restrict__ bias, const float* __restrict__ xT,
    const float* __restrict__ hr, float* __restrict__ hw,
    float* __restrict__ cT, float* __restrict__ zpart,
    unsigned int* cntA, int t) {
  const int tid = threadIdx.x;
  const int lane = tid & 63;
  const int strip = __builtin_amdgcn_readfirstlane(tid >> 6);
  const int jt = blockIdx.x >> 3;
  const int e = blockIdx.x & 7;
  const int cs = lane >> 3;
  const int bg = lane & 7;
  const int m = jt & 15;

  __shared__ float red[4][64][33];
  __shared__ int lastf;

  float acc[32];
#pragma unroll
  for (int b = 0; b < 32; ++b) acc[b] = 0.f;

  const int klo = e * 224 + strip * 28;
  const int wcol = jt * 64 + cs * 8;

#define XROW(k) ((k) < XROWS ? (xT + (size_t)(k) * 32) \
                             : (hr + (size_t)((k) - XROWS) * 32))
#define WROW(k) ((k) < XROWS ? (Km + (size_t)(k) * 4096) \
                             : (Rm + (size_t)((k) - XROWS) * 4096))
  float4 A0[4], B0[4], A1[4], B1[4], X[4];
#pragma unroll
  for (int d = 0; d < 4; ++d) {
    A0[d] = LD4(WROW(klo + d) + wcol);
    B0[d] = LD4(WROW(klo + d) + wcol + 4);
  }
#pragma unroll
  for (int g = 0; g < 3; ++g) {
    const int kb = klo + g * 8;
#pragma unroll
    for (int d = 0; d < 4; ++d) X[d] = LD4(XROW(kb + d) + bg * 4);
#pragma unroll
    for (int d = 0; d < 4; ++d) {
      A1[d] = LD4(WROW(kb + 4 + d) + wcol);
      B1[d] = LD4(WROW(kb + 4 + d) + wcol + 4);
    }
#pragma unroll
    for (int d = 0; d < 4; ++d) fma_8x4(acc, A0[d], B0[d], X[d]);
#pragma unroll
    for (int d = 0; d < 4; ++d) X[d] = LD4(XROW(kb + 4 + d) + bg * 4);
#pragma unroll
    for (int d = 0; d < 4; ++d) {
      A0[d] = LD4(WROW(kb + 8 + d) + wcol);
      B0[d] = LD4(WROW(kb + 8 + d) + wcol + 4);
    }
#pragma unroll
    for (int d = 0; d < 4; ++d) fma_8x4(acc, A1[d], B1[d], X[d]);
  }
  // epilogue: group 6 (rows klo+24 .. klo+27) already in A0/B0
#pragma unroll
  for (int d = 0; d < 4; ++d) X[d] = LD4(XROW(klo + 24 + d) + bg * 4);
#pragma unroll
  for (int d = 0; d < 4; ++d) fma_8x4(acc, A0[d], B0[d], X[d]);
#undef XROW
#undef WROW

  if (strip < 4) {
#pragma unroll
    for (int c = 0; c < 8; ++c)
#pragma unroll
      for (int bb = 0; bb < 4; ++bb)
        red[strip][cs * 8 + c][bg * 4 + bb] = acc[c * 4 + bb];
  }
  __syncthreads();
  if (strip >= 4) {
#pragma unroll
    for (int c = 0; c < 8; ++c)
#pragma unroll
      for (int bb = 0; bb < 4; ++bb)
        red[strip - 4][cs * 8 + c][bg * 4 + bb] += acc[c * 4 + bb];
  }
  __syncthreads();

#pragma unroll
  for (int it = 0; it < 4; ++it) {
    int idx = it * 512 + tid;
    int col = idx >> 5, b = idx & 31;
    float s = ((red[0][col][b] + red[1][col][b]) + red[2][col][b]) +
              red[3][col][b];
    zpart[((size_t)e * 4096 + jt * 64 + col) * 32 + b] = s;
  }
  __syncthreads();
  if (tid == 0) {
    __threadfence();
    unsigned int old = atomicAdd(&cntA[t * 16 + m], 1u);
    lastf = (old == 31u);
  }
  __syncthreads();

  if (lastf) {
    __threadfence();
#pragma unroll
    for (int it = 0; it < 4; ++it) {
      int idx = it * 512 + tid;
      int ul = idx >> 5, b = idx & 31;
      int u = m * 64 + ul;
      float zs[4];
#pragma unroll
      for (int g = 0; g < 4; ++g) {
        int jj = g * 1024 + u;
        const float* zp = zpart + (size_t)jj * 32 + b;
        float s = zp[0];
#pragma unroll
        for (int ee = 1; ee < 8; ++ee) s += zp[(size_t)ee * 4096 * 32];
        zs[g] = s + bias[jj];
      }
      float ig = 1.0f / (1.0f + expf(-zs[0]));
      float fg = 1.0f / (1.0f + expf(-zs[1]));
      float og = 1.0f / (1.0f + expf(-zs[3]));
      float cold = cT[(size_t)u * 32 + b];
      float cn = fg * cold + ig * tanhf(zs[2]);
      cT[(size_t)u * 32 + b] = cn;
      hw[(size_t)u * 32 + b] = og * tanhf(cn);
    }
  }
}

// ---------------------------------------------------------------------------
// Logits + gumbel + argmax + sample + embedding gather.
// Grid 500 (64 vocab cols each) x block 512 (8 wave-strips of 128 h-rows).
// Lane (cs=lane>>3, bg=lane&7) owns cols v0 + cs*8 + [0,8) x batches
// bg*4 + [0,4). 128 k-rows = 32 groups of 4, ping-pong pipelined: X group
// issued first (its vmcnt wait leaves the 8 weight loads of the NEXT group
// outstanding), weights double-buffered one group ahead.
__global__ __launch_bounds__(512, 4) void k_logits(
    const float* __restrict__ Pw, const float* __restrict__ pb,
    const float* __restrict__ emb, const float* __restrict__ hr,
    float* __restrict__ xT, unsigned long long* winners,
    unsigned int* cntB, int* __restrict__ out, int t, uint32_t s0,
    uint32_t s1) {
  const int tid = threadIdx.x;
  const int lane = tid & 63;
  const int strip = __builtin_amdgcn_readfirstlane(tid >> 6);
  const int v0 = blockIdx.x * 64;
  const int cs = lane >> 3;
  const int bg = lane & 7;

  __shared__ float red[4][64][33];
  __shared__ unsigned long long wbs[32][17];
  __shared__ int samp[BATCH];
  __shared__ int lastf;

  float acc[32];
#pragma unroll
  for (int b = 0; b < 32; ++b) acc[b] = 0.f;

  {
    const float* xp = hr + (size_t)(strip * 128) * 32 + bg * 4;
    const float* wp = Pw + (size_t)(strip * 128) * VOCAB + v0 + cs * 8;
    float4 A0[4], B0[4], A1[4], B1[4], X[4];
#pragma unroll
    for (int d = 0; d < 4; ++d) {
      A0[d] = LD4(wp + (size_t)d * VOCAB);
      B0[d] = LD4(wp + (size_t)d * VOCAB + 4);
    }
    for (int it = 0; it < 16; ++it) {
      // even group (rows 8*it .. +3): compute from buf0, prefetch buf1
#pragma unroll
      for (int d = 0; d < 4; ++d) X[d] = LD4(xp + d * 32);
#pragma unroll
      for (int d = 0; d < 4; ++d) {
        A1[d] = LD4(wp + (size_t)(4 + d) * VOCAB);
        B1[d] = LD4(wp + (size_t)(4 + d) * VOCAB + 4);
      }
#pragma unroll
      for (int d = 0; d < 4; ++d) fma_8x4(acc, A0[d], B0[d], X[d]);
      // odd group (rows 8*it+4 .. +7): compute from buf1, prefetch buf0
#pragma unroll
      for (int d = 0; d < 4; ++d) X[d] = LD4(xp + 128 + d * 32);
      if (it < 15) {
#pragma unroll
        for (int d = 0; d < 4; ++d) {
          A0[d] = LD4(wp + (size_t)(8 + d) * VOCAB);
          B0[d] = LD4(wp + (size_t)(8 + d) * VOCAB + 4);
        }
      }
#pragma unroll
      for (int d = 0; d < 4; ++d) fma_8x4(acc, A1[d], B1[d], X[d]);
      xp += 256;
      wp += (size_t)8 * VOCAB;
    }
  }

  if (strip < 4) {
#pragma unroll
    for (int c = 0; c < 8; ++c)
#pragma unroll
      for (int bb = 0; bb < 4; ++bb)
        red[strip][cs * 8 + c][bg * 4 + bb] = acc[c * 4 + bb];
  }
  __syncthreads();
  if (strip >= 4) {
#pragma unroll
    for (int c = 0; c < 8; ++c)
#pragma unroll
      for (int bb = 0; bb < 4; ++bb)
        red[strip - 4][cs * 8 + c][bg * 4 + bb] += acc[c * 4 + bb];
  }
  __syncthreads();

#pragma unroll
  for (int it = 0; it < 4; ++it) {
    int idx = it * 512 + tid;
    int col = idx >> 5, b = idx & 31;
    float s = ((red[0][col][b] + red[1][col][b]) + red[2][col][b]) +
              red[3][col][b] + pb[v0 + col];
    red[0][col][b] = s;
  }
  __syncthreads();

  {
    const int b = tid & 31;
    const int sub = tid >> 5;
    unsigned long long best = 0ull;
#pragma unroll
    for (int c = 0; c < 4; ++c) {
      int col = sub * 4 + c;
      int vv = v0 + col;
      float logit = red[0][col][b];
      uint32_t y0, y1;
      tf2x32(s0, s1, 0u, (uint32_t)(b * VOCAB + vv), y0, y1);
      uint32_t bits = y0 ^ y1;  // jax partitionable 32-bit random_bits
      uint32_t fb = (bits >> 9) | 0x3F800000u;
      float f = __uint_as_float(fb) - 1.0f;
      float u = f + TINYF;
      u = fmaxf(TINYF, u);
      float g = -logf(-logf(u));
      float val = g + logit;
      uint32_t ub = __float_as_uint(val);
      ub = ((int)ub < 0) ? ~ub : (ub | 0x80000000u);
      unsigned long long pk =
          ((unsigned long long)ub << 32) | (uint32_t)(~(uint32_t)vv);
      if (pk > best) best = pk;
    }
    wbs[b][sub] = best;
  }
  __syncthreads();

  if (tid < 32) {
    unsigned long long best = wbs[tid][0];
#pragma unroll
    for (int s = 1; s < 16; ++s)
      best = (wbs[tid][s] > best) ? wbs[tid][s] : best;
    unsigned long long cur = winners[t * 32 + tid];  // stale-ok prune read
    if (best > cur) atomicMax(&winners[t * 32 + tid], best);
  }
  __syncthreads();
  if (tid == 0) {
    __threadfence();
    unsigned int old = atomicAdd(&cntB[t], 1u);
    lastf = (old == 499u);
  }
  __syncthreads();

  if (lastf) {
    __threadfence();
    if (tid < 32) {
      unsigned long long w = atomicMax(&winners[t * 32 + tid], 0ull);
      int vv = (int)(~(uint32_t)(w & 0xFFFFFFFFull));
      samp[tid] = vv;
      out[tid * STEPS + t] = vv;
    }
    __syncthreads();
#pragma unroll
    for (int it = 0; it < 16; ++it) {
      int idx = it * 512 + tid;
      int b = idx >> 8, e2 = idx & 255;
      xT[(size_t)e2 * 32 + b] = emb[(size_t)samp[b] * EMB + e2];
    }
  }
}

// ---------------------------------------------------------------------------
extern "C" void kernel_launch(void* const* d_in, const int* in_sizes, int n_in,
                              void* d_out, int out_size, void* d_ws,
                              size_t ws_size, hipStream_t stream) {
  (void)in_sizes; (void)n_in; (void)out_size; (void)ws_size;
  const float* img  = (const float*)d_in[0];
  const float* emb  = (const float*)d_in[1];
  const float* Km   = (const float*)d_in[2];
  const float* Rm   = (const float*)d_in[3];
  const float* bias = (const float*)d_in[4];
  const float* Pw   = (const float*)d_in[5];
  const float* pb   = (const float*)d_in[6];
  int* out = (int*)d_out;

  char* ws = (char*)d_ws;
  unsigned long long* winners = (unsigned long long*)(ws + 0);
  unsigned int* cntA = (unsigned int*)(ws + 32768);
  unsigned int* cntB = (unsigned int*)(ws + 40960);
  float* xT   = (float*)(ws + 49152);
  float* hb0  = (float*)(ws + 147456);
  float* hb1  = (float*)(ws + 278528);
  float* cT   = (float*)(ws + 409600);
  float* zpart = (float*)(ws + 540672);

  k_init<<<377, 256, 0, stream>>>(img, emb, xT, hb0, cT, winners, cntA, cntB);

  // Host-side key chain (pure, identical every call -> graph-capture safe).
  uint32_t k0 = 0u, k1 = 42u;  // jax.random.key(42) -> [0, 42]
  for (int t = 0; t < STEPS; ++t) {
    uint32_t n0, n1, su0, su1;
    tf2x32(k0, k1, 0u, 0u, n0, n1);   // split row 0 -> new key
    tf2x32(k0, k1, 0u, 1u, su0, su1); // split row 1 -> subkey
    k0 = n0; k1 = n1;

    const float* hrd = (t & 1) ? hb1 : hb0;
    float* hwr = (t & 1) ? hb0 : hb1;
    k_lstm<<<512, 512, 0, stream>>>(Km, Rm, bias, xT, hrd, hwr, cT, zpart,
                                    cntA, t);
    k_logits<<<500, 512, 0, stream>>>(Pw, pb, emb, hwr, xT, winners, cntB,
                                      out, t, su0, su1);
  }
}

// Round 7
// 29796.310 us; speedup vs baseline: 1.3725x; 1.3725x over previous
//
#include <hip/hip_runtime.h>
#include <cstdint>
#include <cstddef>

// ---------------------------------------------------------------------------
// BaseDecoder: 128-step LSTM decoder with jax.random.categorical sampling.
//
// Structure per call (all on `stream`, graph-capture safe):
//   k_init                      : features mean-pool, x init (emb[1]), zero h/c,
//                                 zero winners/counters (ws is poisoned each call)
//   128 x { k_lstm, k_logits }  : LSTM step (z = x@K + h@R + b, cell update),
//                                 logits + gumbel + argmax + embed gather
//
// v7 = v3 (best, scalar 2-row broadcast drains) + 2-way k-split of k_logits:
//   grid 500 -> 1000; block (tile,half) covers 64 vocab cols x 512 h-rows,
//   so per-wave lgkm drains drop 64 -> 32 and ~4 blocks/CU become resident
//   (vs 2) to hide the remaining scalar-miss latency. Pair combine: ticket
//   parity on cntC[tile] (monotone across steps, no reset); first-arriver
//   stores its 64x32 partial to zlog (reuses the zpart region -- k_lstm
//   rewrites zpart fully each step BEFORE k_logits, stream-ordered) and
//   bumps doneF[tile]; second-arriver spins (bounded: partner ticketed
//   earlier so is already running), adds partner + pb (2-operand fp add is
//   commutative -> deterministic bits), then runs the unchanged
//   gumbel/argmax/winners path. cntB counts the 500 finishers.
//   k_lstm and the inner FMA/drain loop are byte-identical to v3.
//
// PRNG: JAX threefry, *partitionable* variant (default since jax 0.5):
//   split(key)  -> row_i = threefry(key, (0, i)) (both words)
//   bits(i)     = w0 ^ w1 of threefry(subkey, (0, i)), i = b*32000 + v
//   uniform     = bitcast((bits>>9)|0x3f800000) - 1, max(tiny, . + tiny)
//   gumbel      = -log(-log(u)); sample = argmax(logits + gumbel), first index
// Key chain computed on host (pure, same every call) and passed as args.
//
// ws layout (needs ~4.75 MB):
//   [0       ) winners  128*32 u64      (packed argmax, atomicMax)
//   [32768   ) cntA     128*16 u32      (lstm split-k group counters)
//   [40960   ) cntB     128    u32      (logits finisher counters)
//   [43008   ) cntC     500    u32      (logits pair ticket, monotone)
//   [45008   ) doneF    500    u32      (logits pair publication, monotone)
//   [49152   ) xT       768*32 f32      (x transposed [row][batch]; rows 0-255
//                                        emb[sample], 256-767 features)
//   [147456  ) hb0      1024*32 f32     (h ping)
//   [278528  ) hb1      1024*32 f32     (h pong)
//   [409600  ) cT       1024*32 f32     (cell state [u][b])
//   [540672  ) zpart    8*4096*32 f32   (split-k partials of z; ALSO reused
//                                        within each step by k_logits as
//                                        zlog[500][64][32] pair partials)
// ---------------------------------------------------------------------------

#define VOCAB 32000
#define EMB 256
#define UNITS 1024
#define STEPS 128
#define BATCH 32
#define XROWS 768
#define TINYF 1.17549435e-38f

typedef uint32_t u32x16 __attribute__((ext_vector_type(16)));

// Threefry-2x32, 20 rounds (matches jax._src.prng exactly).
__host__ __device__ __forceinline__ void tf2x32(uint32_t k0, uint32_t k1,
                                                uint32_t x0, uint32_t x1,
                                                uint32_t& o0, uint32_t& o1) {
  uint32_t ks2 = k0 ^ k1 ^ 0x1BD11BDAu;
#define TFR(r) { x0 += x1; x1 = (x1 << (r)) | (x1 >> (32 - (r))); x1 ^= x0; }
  x0 += k0; x1 += k1;
  TFR(13) TFR(15) TFR(26) TFR(6)  x0 += k1;  x1 += ks2 + 1u;
  TFR(17) TFR(29) TFR(16) TFR(24) x0 += ks2; x1 += k0 + 2u;
  TFR(13) TFR(15) TFR(26) TFR(6)  x0 += k0;  x1 += k1 + 3u;
  TFR(17) TFR(29) TFR(16) TFR(24) x0 += k1;  x1 += ks2 + 4u;
  TFR(13) TFR(15) TFR(26) TFR(6)  x0 += ks2; x1 += k0 + 5u;
#undef TFR
  o0 = x0; o1 = x1;
}

// Wave-uniform broadcast load of TWO consecutive activation rows (64 floats,
// rows are 128 B apart and contiguous) through the scalar path:
// 4x s_load_dwordx16 + ONE lgkmcnt(0) drain. p MUST be wave-uniform.
__device__ __forceinline__ void sload2_b(const float* p, u32x16& a, u32x16& b,
                                         u32x16& c, u32x16& d) {
  asm volatile("s_load_dwordx16 %0, %4, 0x0\n\t"
               "s_load_dwordx16 %1, %4, 0x40\n\t"
               "s_load_dwordx16 %2, %4, 0x80\n\t"
               "s_load_dwordx16 %3, %4, 0xc0\n\t"
               "s_waitcnt lgkmcnt(0)"
               : "=&s"(a), "=&s"(b), "=&s"(c), "=&s"(d)
               : "s"(p));
}

__device__ __forceinline__ void fma32(float* acc, float w,
                                      const u32x16& xa, const u32x16& xb) {
#pragma unroll
  for (int b = 0; b < 16; ++b)
    acc[b] = fmaf(w, __uint_as_float(xa[b]), acc[b]);
#pragma unroll
  for (int b = 0; b < 16; ++b)
    acc[b + 16] = fmaf(w, __uint_as_float(xb[b]), acc[b + 16]);
}

// ---------------------------------------------------------------------------
__global__ __launch_bounds__(256) void k_init(
    const float* __restrict__ img, const float* __restrict__ emb,
    float* __restrict__ xT, float* __restrict__ h0, float* __restrict__ cT,
    unsigned long long* __restrict__ winners, unsigned int* __restrict__ cntA,
    unsigned int* __restrict__ cntB, unsigned int* __restrict__ cntCD) {
  int idx = blockIdx.x * 256 + threadIdx.x;
  if (idx < 16384) {                       // features: mean over 200 positions
    int b = idx >> 9, ch = idx & 511;
    const float* p = img + (size_t)b * 102400 + ch;
    float s = 0.f;
    for (int t = 0; t < 200; ++t) s += p[(size_t)t * 512];
    xT[(size_t)(256 + ch) * 32 + b] = s / 200.0f;
  } else if (idx < 24576) {                // start token embedding (row 1)
    int i2 = idx - 16384;
    int e = i2 >> 5, b = i2 & 31;
    xT[(size_t)e * 32 + b] = emb[256 + e];
  } else if (idx < 57344) {
    h0[idx - 24576] = 0.f;
  } else if (idx < 90112) {
    cT[idx - 57344] = 0.f;
  } else if (idx < 94208) {
    winners[idx - 90112] = 0ull;
  } else if (idx < 96256) {
    cntA[idx - 94208] = 0u;
  } else if (idx < 96384) {
    cntB[idx - 96256] = 0u;
  } else if (idx < 97384) {                // cntC[500] + doneF[500] contiguous
    cntCD[idx - 96384] = 0u;
  }
}

// ---------------------------------------------------------------------------
// LSTM step (identical to v3). Grid 512 = 64 column-tiles x 8 k-eighths.
// Block 512 = 8 wave-strips x 64 lanes(columns). Last block of each group of
// 32 (same hidden-unit tile) performs the cell update into cT / hw.
// k range per strip is 28 rows = 14 pairs; pairs never straddle the xT->hr
// boundary (row 768) because klo and 768 are both even.
__global__ __launch_bounds__(512) void k_lstm(
    const float* __restrict__ Km, const float* __restrict__ Rm,
    const float* __restrict__ bias, const float* __restrict__ xT,
    const float* __restrict__ hr, float* __restrict__ hw,
    float* __restrict__ cT, float* __restrict__ zpart,
    unsigned int* cntA, int t) {
  const int tid = threadIdx.x;
  const int lane = tid & 63;
  const int strip = __builtin_amdgcn_readfirstlane(tid >> 6);
  const int jt = blockIdx.x >> 3;
  const int e = blockIdx.x & 7;
  const int j = jt * 64 + lane;
  const int m = jt & 15;

  __shared__ float red[4][64][33];
  __shared__ int lastf;

  float acc[32];
#pragma unroll
  for (int b = 0; b < 32; ++b) acc[b] = 0.f;

  const int klo = e * 224 + strip * 28;
  const int khi = klo + 28;

#define WROW(g) ((g) < XROWS ? Km[(size_t)(g) * 4096 + j] \
                             : Rm[(size_t)((g) - XROWS) * 4096 + j])
  float wc0 = WROW(klo);
  float wc1 = WROW(klo + 1);
  for (int k = klo; k < khi; k += 2) {
    float wn0 = 0.f, wn1 = 0.f;
    if (k + 2 < khi) { wn0 = WROW(k + 2); wn1 = WROW(k + 3); }
    const float* xrow = (k < XROWS) ? (xT + (size_t)k * 32)
                                    : (hr + (size_t)(k - XROWS) * 32);
    u32x16 xa, xb, xc, xd;
    sload2_b(xrow, xa, xb, xc, xd);
    fma32(acc, wc0, xa, xb);
    fma32(acc, wc1, xc, xd);
    wc0 = wn0; wc1 = wn1;
  }
#undef WROW

  if (strip < 4) {
#pragma unroll
    for (int b = 0; b < 32; ++b) red[strip][lane][b] = acc[b];
  }
  __syncthreads();
  if (strip >= 4) {
#pragma unroll
    for (int b = 0; b < 32; ++b) red[strip - 4][lane][b] += acc[b];
  }
  __syncthreads();

#pragma unroll
  for (int it = 0; it < 4; ++it) {
    int idx = it * 512 + tid;
    int col = idx >> 5, b = idx & 31;
    float s = ((red[0][col][b] + red[1][col][b]) + red[2][col][b]) +
              red[3][col][b];
    zpart[((size_t)e * 4096 + jt * 64 + col) * 32 + b] = s;
  }
  __syncthreads();
  if (tid == 0) {
    __threadfence();
    unsigned int old = atomicAdd(&cntA[t * 16 + m], 1u);
    lastf = (old == 31u);
  }
  __syncthreads();

  if (lastf) {
    __threadfence();
#pragma unroll
    for (int it = 0; it < 4; ++it) {
      int idx = it * 512 + tid;
      int ul = idx >> 5, b = idx & 31;
      int u = m * 64 + ul;
      float zs[4];
#pragma unroll
      for (int g = 0; g < 4; ++g) {
        int jj = g * 1024 + u;
        const float* zp = zpart + (size_t)jj * 32 + b;
        float s = zp[0];
#pragma unroll
        for (int ee = 1; ee < 8; ++ee) s += zp[(size_t)ee * 4096 * 32];
        zs[g] = s + bias[jj];
      }
      float ig = 1.0f / (1.0f + expf(-zs[0]));
      float fg = 1.0f / (1.0f + expf(-zs[1]));
      float og = 1.0f / (1.0f + expf(-zs[3]));
      float cold = cT[(size_t)u * 32 + b];
      float cn = fg * cold + ig * tanhf(zs[2]);
      cT[(size_t)u * 32 + b] = cn;
      hw[(size_t)u * 32 + b] = og * tanhf(cn);
    }
  }
}

// ---------------------------------------------------------------------------
// Logits + gumbel + argmax + sample + embedding gather, 2-way k-split.
// Grid 1000: block = (tile = bid>>1, half = bid&1); covers cols
// [tile*64, +64) x h-rows [half*512, +512). 8 wave-strips of 64 rows each
// (32 lgkm drains per wave). Pair combine via cntC parity ticket + doneF
// publication; second-arriver finishes (gumbel/argmax identical to v3).
__global__ __launch_bounds__(512) void k_logits(
    const float* __restrict__ Pw, const float* __restrict__ pb,
    const float* __restrict__ emb, const float* __restrict__ hr,
    float* __restrict__ xT, unsigned long long* winners,
    unsigned int* cntB, unsigned int* cntC, unsigned int* doneF,
    float* __restrict__ zlog, int* __restrict__ out, int t, uint32_t s0,
    uint32_t s1) {
  const int tid = threadIdx.x;
  const int lane = tid & 63;
  const int strip = __builtin_amdgcn_readfirstlane(tid >> 6);
  const int tile = blockIdx.x >> 1;
  const int half = blockIdx.x & 1;
  const int v0 = tile * 64;

  __shared__ float red[4][64][33];
  __shared__ unsigned long long wbs[32][17];
  __shared__ int samp[BATCH];
  __shared__ int lastf;
  __shared__ int roleS;

  float acc[32];
#pragma unroll
  for (int b = 0; b < 32; ++b) acc[b] = 0.f;

  {
    const int r0 = half * 512 + strip * 64;
    const float* xp = hr + (size_t)r0 * 32;
    const float* wp = Pw + (size_t)r0 * VOCAB + v0 + lane;
    float wc0 = wp[0], wc1 = wp[VOCAB], wc2 = wp[2 * VOCAB],
          wc3 = wp[3 * VOCAB];
    const float* wpp = wp + (size_t)4 * VOCAB;
    u32x16 xa, xb, xc, xd;
    for (int k = 0; k < 60; k += 4) {
      float wn0 = wpp[0], wn1 = wpp[VOCAB], wn2 = wpp[2 * VOCAB],
            wn3 = wpp[3 * VOCAB];
      wpp += (size_t)4 * VOCAB;
      sload2_b(xp, xa, xb, xc, xd); xp += 64;
      fma32(acc, wc0, xa, xb);
      fma32(acc, wc1, xc, xd);
      sload2_b(xp, xa, xb, xc, xd); xp += 64;
      fma32(acc, wc2, xa, xb);
      fma32(acc, wc3, xc, xd);
      wc0 = wn0; wc1 = wn1; wc2 = wn2; wc3 = wn3;
    }
    sload2_b(xp, xa, xb, xc, xd); xp += 64;
    fma32(acc, wc0, xa, xb);
    fma32(acc, wc1, xc, xd);
    sload2_b(xp, xa, xb, xc, xd);
    fma32(acc, wc2, xa, xb);
    fma32(acc, wc3, xc, xd);
  }

  if (strip < 4) {
#pragma unroll
    for (int b = 0; b < 32; ++b) red[strip][lane][b] = acc[b];
  }
  __syncthreads();
  if (strip >= 4) {
#pragma unroll
    for (int b = 0; b < 32; ++b) red[strip - 4][lane][b] += acc[b];
  }
  __syncthreads();

  // Fold strips (no pb yet): sv[it] is this block's half-partial.
  float sv[4];
#pragma unroll
  for (int it = 0; it < 4; ++it) {
    int idx = it * 512 + tid;
    int col = idx >> 5, b = idx & 31;
    sv[it] = ((red[0][col][b] + red[1][col][b]) + red[2][col][b]) +
             red[3][col][b];
  }

  // Pair ticket: even = first-arriver (store & leave), odd = finisher.
  if (tid == 0) roleS = (int)(atomicAdd(&cntC[tile], 1u) & 1u);
  __syncthreads();

  float* zt = zlog + (size_t)tile * 2048;
  if (roleS == 0) {
    // First-arriver: publish partial, bump doneF, exit.
#pragma unroll
    for (int it = 0; it < 4; ++it) zt[it * 512 + tid] = sv[it];
    __syncthreads();
    if (tid == 0) {
      __threadfence();
      atomicAdd(&doneF[tile], 1u);
    }
    return;
  }

  // Finisher: stash own partial in red[0], wait for partner, combine.
#pragma unroll
  for (int it = 0; it < 4; ++it) {
    int idx = it * 512 + tid;
    red[0][idx >> 5][idx & 31] = sv[it];
  }
  if (tid == 0) {
    while (atomicMax(&doneF[tile], 0u) < (unsigned)(t + 1)) {}
  }
  __syncthreads();
  __threadfence();
#pragma unroll
  for (int it = 0; it < 4; ++it) {
    int idx = it * 512 + tid;
    int col = idx >> 5, b = idx & 31;
    red[0][col][b] = (red[0][col][b] + zt[idx]) + pb[v0 + col];
  }
  __syncthreads();

  {
    const int b = tid & 31;
    const int sub = tid >> 5;
    unsigned long long best = 0ull;
#pragma unroll
    for (int c = 0; c < 4; ++c) {
      int col = sub * 4 + c;
      int vv = v0 + col;
      float logit = red[0][col][b];
      uint32_t y0, y1;
      tf2x32(s0, s1, 0u, (uint32_t)(b * VOCAB + vv), y0, y1);
      uint32_t bits = y0 ^ y1;  // jax partitionable 32-bit random_bits
      uint32_t fb = (bits >> 9) | 0x3F800000u;
      float f = __uint_as_float(fb) - 1.0f;
      float u = f + TINYF;
      u = fmaxf(TINYF, u);
      float g = -logf(-logf(u));
      float val = g + logit;
      uint32_t ub = __float_as_uint(val);
      ub = ((int)ub < 0) ? ~ub : (ub | 0x80000000u);
      unsigned long long pk =
          ((unsigned long long)ub << 32) | (uint32_t)(~(uint32_t)vv);
      if (pk > best) best = pk;
    }
    wbs[b][sub] = best;
  }
  __syncthreads();

  if (tid < 32) {
    unsigned long long best = wbs[tid][0];
#pragma unroll
    for (int s = 1; s < 16; ++s)
      best = (wbs[tid][s] > best) ? wbs[tid][s] : best;
    unsigned long long cur = winners[t * 32 + tid];  // stale-ok prune read
    if (best > cur) atomicMax(&winners[t * 32 + tid], best);
  }
  __syncthreads();
  if (tid == 0) {
    __threadfence();
    unsigned int old = atomicAdd(&cntB[t], 1u);
    lastf = (old == 499u);
  }
  __syncthreads();

  if (lastf) {
    __threadfence();
    if (tid < 32) {
      unsigned long long w = atomicMax(&winners[t * 32 + tid], 0ull);
      int vv = (int)(~(uint32_t)(w & 0xFFFFFFFFull));
      samp[tid] = vv;
      out[tid * STEPS + t] = vv;
    }
    __syncthreads();
#pragma unroll
    for (int it = 0; it < 16; ++it) {
      int idx = it * 512 + tid;
      int b = idx >> 8, e2 = idx & 255;
      xT[(size_t)e2 * 32 + b] = emb[(size_t)samp[b] * EMB + e2];
    }
  }
}

// ---------------------------------------------------------------------------
extern "C" void kernel_launch(void* const* d_in, const int* in_sizes, int n_in,
                              void* d_out, int out_size, void* d_ws,
                              size_t ws_size, hipStream_t stream) {
  (void)in_sizes; (void)n_in; (void)out_size; (void)ws_size;
  const float* img  = (const float*)d_in[0];
  const float* emb  = (const float*)d_in[1];
  const float* Km   = (const float*)d_in[2];
  const float* Rm   = (const float*)d_in[3];
  const float* bias = (const float*)d_in[4];
  const float* Pw   = (const float*)d_in[5];
  const float* pb   = (const float*)d_in[6];
  int* out = (int*)d_out;

  char* ws = (char*)d_ws;
  unsigned long long* winners = (unsigned long long*)(ws + 0);
  unsigned int* cntA = (unsigned int*)(ws + 32768);
  unsigned int* cntB = (unsigned int*)(ws + 40960);
  unsigned int* cntC = (unsigned int*)(ws + 43008);  // [500]
  unsigned int* doneF = (unsigned int*)(ws + 45008); // [500], contiguous after
  float* xT   = (float*)(ws + 49152);
  float* hb0  = (float*)(ws + 147456);
  float* hb1  = (float*)(ws + 278528);
  float* cT   = (float*)(ws + 409600);
  float* zpart = (float*)(ws + 540672);

  k_init<<<381, 256, 0, stream>>>(img, emb, xT, hb0, cT, winners, cntA, cntB,
                                  cntC /* covers cntC+doneF, 1000 u32 */);

  // Host-side key chain (pure, identical every call -> graph-capture safe).
  uint32_t k0 = 0u, k1 = 42u;  // jax.random.key(42) -> [0, 42]
  for (int t = 0; t < STEPS; ++t) {
    uint32_t n0, n1, su0, su1;
    tf2x32(k0, k1, 0u, 0u, n0, n1);   // split row 0 -> new key
    tf2x32(k0, k1, 0u, 1u, su0, su1); // split row 1 -> subkey
    k0 = n0; k1 = n1;

    const float* hrd = (t & 1) ? hb1 : hb0;
    float* hwr = (t & 1) ? hb0 : hb1;
    k_lstm<<<512, 512, 0, stream>>>(Km, Rm, bias, xT, hrd, hwr, cT, zpart,
                                    cntA, t);
    // zpart is reused as zlog: k_lstm fully rewrites it next step before
    // k_logits reads it again (stream-ordered), so no conflict.
    k_logits<<<1000, 512, 0, stream>>>(Pw, pb, emb, hwr, xT, winners, cntB,
                                       cntC, doneF, zpart, out, t, su0, su1);
  }
}

// Round 8
// 18309.784 us; speedup vs baseline: 2.2334x; 1.6273x over previous
//
#include <hip/hip_runtime.h>
#include <cstdint>
#include <cstddef>

// ---------------------------------------------------------------------------
// BaseDecoder: 128-step LSTM decoder with jax.random.categorical sampling.
//
// Structure per call (all on `stream`, graph-capture safe):
//   k_init                      : features mean-pool, x init (emb[1]), zero h/c,
//                                 zero winners/counters (ws is poisoned each call)
//   128 x { k_lstm, k_logits }  : LSTM step (z = x@K + h@R + b, cell update),
//                                 logits + gumbel + argmax + embed gather
//
// v8 = v3 (scalar broadcast path) + BATCH-SPLIT blocks (sync-free v7):
//   each block covers 64 cols x 16 batches (bh = batch half). A row's
//   16-batch slice is 64 B = one s_load_dwordx16, so a 4-load lgkm drain
//   covers 4 rows: drains/wave halve (logits 64->32, lstm 14->7) at the
//   same FMA-per-drain. Grids double (1000 / 1024 -> ~4 blocks/CU) so
//   ~8 waves/SIMD cover the remaining scalar-miss stalls. No cross-block
//   coupling: gumbel/argmax is per-(batch,col) so each block finishes its
//   own 16 batches into winners (cntB -> 999); k_lstm's cntA group = 64
//   blocks, cell-update finisher unchanged (reads both batch halves).
//   Per-output FMA order (k ascending, strip-fold tree, zpart ee-sum) is
//   bit-identical to v3. Lessons kept: no VGPR-capping launch bounds
//   (v2/v6 spills), no inter-block spin (v7).
//
// PRNG: JAX threefry, *partitionable* variant (default since jax 0.5):
//   split(key)  -> row_i = threefry(key, (0, i)) (both words)
//   bits(i)     = w0 ^ w1 of threefry(subkey, (0, i)), i = b*32000 + v
//   uniform     = bitcast((bits>>9)|0x3f800000) - 1, max(tiny, . + tiny)
//   gumbel      = -log(-log(u)); sample = argmax(logits + gumbel), first index
// Key chain computed on host (pure, same every call) and passed as args.
//
// ws layout (needs ~4.75 MB):
//   [0       ) winners  128*32 u64      (packed argmax, atomicMax)
//   [32768   ) cntA     128*16 u32      (lstm split-k group counters, to 64)
//   [40960   ) cntB     128    u32      (logits block counters, to 1000)
//   [49152   ) xT       768*32 f32      (x transposed [row][batch]; rows 0-255
//                                        emb[sample], 256-767 features)
//   [147456  ) hb0      1024*32 f32     (h ping)
//   [278528  ) hb1      1024*32 f32     (h pong)
//   [409600  ) cT       1024*32 f32     (cell state [u][b])
//   [540672  ) zpart    8*4096*32 f32   (split-k partials of z)
// ---------------------------------------------------------------------------

#define VOCAB 32000
#define EMB 256
#define UNITS 1024
#define STEPS 128
#define BATCH 32
#define XROWS 768
#define TINYF 1.17549435e-38f

typedef uint32_t u32x16 __attribute__((ext_vector_type(16)));

// Threefry-2x32, 20 rounds (matches jax._src.prng exactly).
__host__ __device__ __forceinline__ void tf2x32(uint32_t k0, uint32_t k1,
                                                uint32_t x0, uint32_t x1,
                                                uint32_t& o0, uint32_t& o1) {
  uint32_t ks2 = k0 ^ k1 ^ 0x1BD11BDAu;
#define TFR(r) { x0 += x1; x1 = (x1 << (r)) | (x1 >> (32 - (r))); x1 ^= x0; }
  x0 += k0; x1 += k1;
  TFR(13) TFR(15) TFR(26) TFR(6)  x0 += k1;  x1 += ks2 + 1u;
  TFR(17) TFR(29) TFR(16) TFR(24) x0 += ks2; x1 += k0 + 2u;
  TFR(13) TFR(15) TFR(26) TFR(6)  x0 += k0;  x1 += k1 + 3u;
  TFR(17) TFR(29) TFR(16) TFR(24) x0 += k1;  x1 += ks2 + 4u;
  TFR(13) TFR(15) TFR(26) TFR(6)  x0 += ks2; x1 += k0 + 5u;
#undef TFR
  o0 = x0; o1 = x1;
}

// Wave-uniform broadcast load of FOUR consecutive rows' 16-batch half-slices
// (64 B each, rows are 128 B apart): 4x s_load_dwordx16 + ONE lgkmcnt(0)
// drain. p MUST be wave-uniform and point at (row, batch-half) base.
__device__ __forceinline__ void sload4h(const float* p, u32x16& a, u32x16& b,
                                        u32x16& c, u32x16& d) {
  asm volatile("s_load_dwordx16 %0, %4, 0x0\n\t"
               "s_load_dwordx16 %1, %4, 0x80\n\t"
               "s_load_dwordx16 %2, %4, 0x100\n\t"
               "s_load_dwordx16 %3, %4, 0x180\n\t"
               "s_waitcnt lgkmcnt(0)"
               : "=&s"(a), "=&s"(b), "=&s"(c), "=&s"(d)
               : "s"(p));
}

__device__ __forceinline__ void fma16(float* acc, float w, const u32x16& x) {
#pragma unroll
  for (int b = 0; b < 16; ++b)
    acc[b] = fmaf(w, __uint_as_float(x[b]), acc[b]);
}

// ---------------------------------------------------------------------------
__global__ __launch_bounds__(256) void k_init(
    const float* __restrict__ img, const float* __restrict__ emb,
    float* __restrict__ xT, float* __restrict__ h0, float* __restrict__ cT,
    unsigned long long* __restrict__ winners, unsigned int* __restrict__ cntA,
    unsigned int* __restrict__ cntB) {
  int idx = blockIdx.x * 256 + threadIdx.x;
  if (idx < 16384) {                       // features: mean over 200 positions
    int b = idx >> 9, ch = idx & 511;
    const float* p = img + (size_t)b * 102400 + ch;
    float s = 0.f;
    for (int t = 0; t < 200; ++t) s += p[(size_t)t * 512];
    xT[(size_t)(256 + ch) * 32 + b] = s / 200.0f;
  } else if (idx < 24576) {                // start token embedding (row 1)
    int i2 = idx - 16384;
    int e = i2 >> 5, b = i2 & 31;
    xT[(size_t)e * 32 + b] = emb[256 + e];
  } else if (idx < 57344) {
    h0[idx - 24576] = 0.f;
  } else if (idx < 90112) {
    cT[idx - 57344] = 0.f;
  } else if (idx < 94208) {
    winners[idx - 90112] = 0ull;
  } else if (idx < 96256) {
    cntA[idx - 94208] = 0u;
  } else if (idx < 96384) {
    cntB[idx - 96256] = 0u;
  }
}

// ---------------------------------------------------------------------------
// LSTM step. Grid 1024 = 64 column-tiles x 8 k-eighths x 2 batch-halves.
// Block 512 = 8 wave-strips x 64 lanes(columns); strip covers 28 k-rows =
// 7 drain-groups of 4 rows (groups never straddle row 768: bases are
// multiples of 4). Last block of each group of 64 (same hidden-unit tile m)
// performs the cell update for ALL 32 batches into cT / hw.
__global__ __launch_bounds__(512) void k_lstm(
    const float* __restrict__ Km, const float* __restrict__ Rm,
    const float* __restrict__ bias, const float* __restrict__ xT,
    const float* __restrict__ hr, float* __restrict__ hw,
    float* __restrict__ cT, float* __restrict__ zpart,
    unsigned int* cntA, int t) {
  const int tid = threadIdx.x;
  const int lane = tid & 63;
  const int strip = __builtin_amdgcn_readfirstlane(tid >> 6);
  const int bh = blockIdx.x & 1;
  const int e = (blockIdx.x >> 1) & 7;
  const int jt = blockIdx.x >> 4;
  const int j = jt * 64 + lane;
  const int m = jt & 15;
  const int b0 = bh * 16;

  __shared__ float red[4][64][17];
  __shared__ int lastf;

  float acc[16];
#pragma unroll
  for (int b = 0; b < 16; ++b) acc[b] = 0.f;

  const int klo = e * 224 + strip * 28;
  const int khi = klo + 28;

#define WROW(g) ((g) < XROWS ? Km[(size_t)(g) * 4096 + j] \
                             : Rm[(size_t)((g) - XROWS) * 4096 + j])
  float wc0 = WROW(klo);
  float wc1 = WROW(klo + 1);
  float wc2 = WROW(klo + 2);
  float wc3 = WROW(klo + 3);
  for (int k = klo; k < khi; k += 4) {
    float wn0 = 0.f, wn1 = 0.f, wn2 = 0.f, wn3 = 0.f;
    if (k + 4 < khi) {
      wn0 = WROW(k + 4); wn1 = WROW(k + 5);
      wn2 = WROW(k + 6); wn3 = WROW(k + 7);
    }
    const float* xrow = ((k < XROWS) ? (xT + (size_t)k * 32)
                                     : (hr + (size_t)(k - XROWS) * 32)) + b0;
    u32x16 xa, xb, xc, xd;
    sload4h(xrow, xa, xb, xc, xd);
    fma16(acc, wc0, xa);
    fma16(acc, wc1, xb);
    fma16(acc, wc2, xc);
    fma16(acc, wc3, xd);
    wc0 = wn0; wc1 = wn1; wc2 = wn2; wc3 = wn3;
  }
#undef WROW

  if (strip < 4) {
#pragma unroll
    for (int b = 0; b < 16; ++b) red[strip][lane][b] = acc[b];
  }
  __syncthreads();
  if (strip >= 4) {
#pragma unroll
    for (int b = 0; b < 16; ++b) red[strip - 4][lane][b] += acc[b];
  }
  __syncthreads();

#pragma unroll
  for (int it = 0; it < 2; ++it) {
    int idx = it * 512 + tid;
    int col = idx >> 4, bb = idx & 15;
    float s = ((red[0][col][bb] + red[1][col][bb]) + red[2][col][bb]) +
              red[3][col][bb];
    zpart[((size_t)e * 4096 + jt * 64 + col) * 32 + b0 + bb] = s;
  }
  __syncthreads();
  if (tid == 0) {
    __threadfence();
    unsigned int old = atomicAdd(&cntA[t * 16 + m], 1u);
    lastf = (old == 63u);
  }
  __syncthreads();

  if (lastf) {
    __threadfence();
#pragma unroll
    for (int it = 0; it < 4; ++it) {
      int idx = it * 512 + tid;
      int ul = idx >> 5, b = idx & 31;
      int u = m * 64 + ul;
      float zs[4];
#pragma unroll
      for (int g = 0; g < 4; ++g) {
        int jj = g * 1024 + u;
        const float* zp = zpart + (size_t)jj * 32 + b;
        float s = zp[0];
#pragma unroll
        for (int ee = 1; ee < 8; ++ee) s += zp[(size_t)ee * 4096 * 32];
        zs[g] = s + bias[jj];
      }
      float ig = 1.0f / (1.0f + expf(-zs[0]));
      float fg = 1.0f / (1.0f + expf(-zs[1]));
      float og = 1.0f / (1.0f + expf(-zs[3]));
      float cold = cT[(size_t)u * 32 + b];
      float cn = fg * cold + ig * tanhf(zs[2]);
      cT[(size_t)u * 32 + b] = cn;
      hw[(size_t)u * 32 + b] = og * tanhf(cn);
    }
  }
}

// ---------------------------------------------------------------------------
// Logits + gumbel + argmax + sample + embedding gather.
// Grid 1000 = 500 col-tiles x 2 batch-halves; block 512 = 8 wave-strips of
// 128 h-rows = 32 drain-groups of 4 rows. Each block finishes gumbel/argmax
// for its own 16 batches (no cross-block coupling); cntB counts to 1000.
__global__ __launch_bounds__(512) void k_logits(
    const float* __restrict__ Pw, const float* __restrict__ pb,
    const float* __restrict__ emb, const float* __restrict__ hr,
    float* __restrict__ xT, unsigned long long* winners,
    unsigned int* cntB, int* __restrict__ out, int t, uint32_t s0,
    uint32_t s1) {
  const int tid = threadIdx.x;
  const int lane = tid & 63;
  const int strip = __builtin_amdgcn_readfirstlane(tid >> 6);
  const int tile = blockIdx.x >> 1;
  const int bh = blockIdx.x & 1;
  const int v0 = tile * 64;
  const int b0 = bh * 16;

  __shared__ float red[4][64][17];
  __shared__ unsigned long long wbs[16][33];
  __shared__ int samp[BATCH];
  __shared__ int lastf;

  float acc[16];
#pragma unroll
  for (int b = 0; b < 16; ++b) acc[b] = 0.f;

  {
    const float* xp = hr + (size_t)(strip * 128) * 32 + b0;
    const float* wp = Pw + (size_t)(strip * 128) * VOCAB + v0 + lane;
    float wc0 = wp[0], wc1 = wp[VOCAB], wc2 = wp[2 * VOCAB],
          wc3 = wp[3 * VOCAB];
    const float* wpp = wp + (size_t)4 * VOCAB;
    u32x16 xa, xb, xc, xd;
    for (int k = 0; k < 124; k += 4) {
      float wn0 = wpp[0], wn1 = wpp[VOCAB], wn2 = wpp[2 * VOCAB],
            wn3 = wpp[3 * VOCAB];
      wpp += (size_t)4 * VOCAB;
      sload4h(xp, xa, xb, xc, xd); xp += 128;
      fma16(acc, wc0, xa);
      fma16(acc, wc1, xb);
      fma16(acc, wc2, xc);
      fma16(acc, wc3, xd);
      wc0 = wn0; wc1 = wn1; wc2 = wn2; wc3 = wn3;
    }
    sload4h(xp, xa, xb, xc, xd);
    fma16(acc, wc0, xa);
    fma16(acc, wc1, xb);
    fma16(acc, wc2, xc);
    fma16(acc, wc3, xd);
  }

  if (strip < 4) {
#pragma unroll
    for (int b = 0; b < 16; ++b) red[strip][lane][b] = acc[b];
  }
  __syncthreads();
  if (strip >= 4) {
#pragma unroll
    for (int b = 0; b < 16; ++b) red[strip - 4][lane][b] += acc[b];
  }
  __syncthreads();

#pragma unroll
  for (int it = 0; it < 2; ++it) {
    int idx = it * 512 + tid;
    int col = idx >> 4, bb = idx & 15;
    float s = ((red[0][col][bb] + red[1][col][bb]) + red[2][col][bb]) +
              red[3][col][bb] + pb[v0 + col];
    red[0][col][bb] = s;
  }
  __syncthreads();

  {
    const int b = tid & 15;           // local batch (global b0 + b)
    const int sub = tid >> 4;         // 32 subs x 2 cols each
    unsigned long long best = 0ull;
#pragma unroll
    for (int c = 0; c < 2; ++c) {
      int col = sub * 2 + c;
      int vv = v0 + col;
      float logit = red[0][col][b];
      uint32_t y0, y1;
      tf2x32(s0, s1, 0u, (uint32_t)((b0 + b) * VOCAB + vv), y0, y1);
      uint32_t bits = y0 ^ y1;  // jax partitionable 32-bit random_bits
      uint32_t fb = (bits >> 9) | 0x3F800000u;
      float f = __uint_as_float(fb) - 1.0f;
      float u = f + TINYF;
      u = fmaxf(TINYF, u);
      float g = -logf(-logf(u));
      float val = g + logit;
      uint32_t ub = __float_as_uint(val);
      ub = ((int)ub < 0) ? ~ub : (ub | 0x80000000u);
      unsigned long long pk =
          ((unsigned long long)ub << 32) | (uint32_t)(~(uint32_t)vv);
      if (pk > best) best = pk;
    }
    wbs[b][sub] = best;
  }
  __syncthreads();

  if (tid < 16) {
    unsigned long long best = wbs[tid][0];
#pragma unroll
    for (int s = 1; s < 32; ++s)
      best = (wbs[tid][s] > best) ? wbs[tid][s] : best;
    unsigned long long cur = winners[t * 32 + b0 + tid];  // stale-ok prune
    if (best > cur) atomicMax(&winners[t * 32 + b0 + tid], best);
  }
  __syncthreads();
  if (tid == 0) {
    __threadfence();
    unsigned int old = atomicAdd(&cntB[t], 1u);
    lastf = (old == 999u);
  }
  __syncthreads();

  if (lastf) {
    __threadfence();
    if (tid < 32) {
      unsigned long long w = atomicMax(&winners[t * 32 + tid], 0ull);
      int vv = (int)(~(uint32_t)(w & 0xFFFFFFFFull));
      samp[tid] = vv;
      out[tid * STEPS + t] = vv;
    }
    __syncthreads();
#pragma unroll
    for (int it = 0; it < 16; ++it) {
      int idx = it * 512 + tid;
      int b = idx >> 8, e2 = idx & 255;
      xT[(size_t)e2 * 32 + b] = emb[(size_t)samp[b] * EMB + e2];
    }
  }
}

// ---------------------------------------------------------------------------
extern "C" void kernel_launch(void* const* d_in, const int* in_sizes, int n_in,
                              void* d_out, int out_size, void* d_ws,
                              size_t ws_size, hipStream_t stream) {
  (void)in_sizes; (void)n_in; (void)out_size; (void)ws_size;
  const float* img  = (const float*)d_in[0];
  const float* emb  = (const float*)d_in[1];
  const float* Km   = (const float*)d_in[2];
  const float* Rm   = (const float*)d_in[3];
  const float* bias = (const float*)d_in[4];
  const float* Pw   = (const float*)d_in[5];
  const float* pb   = (const float*)d_in[6];
  int* out = (int*)d_out;

  char* ws = (char*)d_ws;
  unsigned long long* winners = (unsigned long long*)(ws + 0);
  unsigned int* cntA = (unsigned int*)(ws + 32768);
  unsigned int* cntB = (unsigned int*)(ws + 40960);
  float* xT   = (float*)(ws + 49152);
  float* hb0  = (float*)(ws + 147456);
  float* hb1  = (float*)(ws + 278528);
  float* cT   = (float*)(ws + 409600);
  float* zpart = (float*)(ws + 540672);

  k_init<<<377, 256, 0, stream>>>(img, emb, xT, hb0, cT, winners, cntA, cntB);

  // Host-side key chain (pure, identical every call -> graph-capture safe).
  uint32_t k0 = 0u, k1 = 42u;  // jax.random.key(42) -> [0, 42]
  for (int t = 0; t < STEPS; ++t) {
    uint32_t n0, n1, su0, su1;
    tf2x32(k0, k1, 0u, 0u, n0, n1);   // split row 0 -> new key
    tf2x32(k0, k1, 0u, 1u, su0, su1); // split row 1 -> subkey
    k0 = n0; k1 = n1;

    const float* hrd = (t & 1) ? hb1 : hb0;
    float* hwr = (t & 1) ? hb0 : hb1;
    k_lstm<<<1024, 512, 0, stream>>>(Km, Rm, bias, xT, hrd, hwr, cT, zpart,
                                     cntA, t);
    k_logits<<<1000, 512, 0, stream>>>(Pw, pb, emb, hwr, xT, winners, cntB,
                                       out, t, su0, su1);
  }
}